// Round 5
// baseline (259.063 us; speedup 1.0000x reference)
//
#include <hip/hip_runtime.h>
#include <hip/hip_bf16.h>

// PointVoxelizer: bitmap-based sorted-unique over bounded key domain.
// combined = batch*GXYZ + x*YZ + y*GZ + z  in [0, 3.2e8)  -> 40MB bitmap.
// rank(combined) = prefix-popcount == jnp.unique's sorted order.
//
// Pass structure (5 dispatches):
//   zero_bitmap : 40MB ulonglong2 stores
//   mark        : hash points, atomicOr bit, store per-point key u (sentinel invalid)
//   block_sum   : popcount bitmap -> per-word u8 counts + per-block(2048w) sums
//   word_prefix : per-block offset via reduction over bsums[0..bid) (L2-resident),
//                 intra-block scan of u8 counts -> per-word prefix; blk0 writes n_voxels
//   enum_map    : block-role split: [0,en_blocks) enumerate set bits -> coords/centers
//                 at row=rank; rest: per-point rank via prefix+popc(below) + tail pad

namespace {

constexpr int GX = 1000, GY = 1000, GZ = 80;   // ceil((pmax-pmin)/vsize) in fp32 == exact
constexpr int YZ = GY * GZ;                    // 80,000
constexpr int GXYZ = GX * YZ;                  // 80,000,000
constexpr int NBATCH = 4;
constexpr int TOTAL_CELLS = GXYZ * NBATCH;     // 320,000,000 (< 2^31)
constexpr int NWORDS = (TOTAL_CELLS + 63) / 64; // 5,000,000 u64 words = 40 MB (even)
constexpr int WPB = 2048;                      // bitmap words per scan block
constexpr int NSCANB = (NWORDS + WPB - 1) / WPB; // 2442
static_assert(NWORDS % 8 == 0, "word_prefix u64 fast path");

// ws layout (bytes):
//   [0,          40e6)  bitmap  u64[NWORDS]
//   [40e6,       60e6)  prefix  u32[NWORDS]
//   [60e6,       65e6)  cnt     u8 [NWORDS]
//   [65e6,    65.01e6)  bsums   u32[NSCANB]
//   [65.1e6,  73.1e6)   upt     u32[N]
constexpr size_t OFF_PREFIX = 40000000;
constexpr size_t OFF_CNT    = 60000000;
constexpr size_t OFF_BSUMS  = 65000000;
constexpr size_t OFF_UPT    = 65100000;

__global__ void zero_bitmap_kernel(ulonglong2* __restrict__ bm2) {
  int i = blockIdx.x * blockDim.x + threadIdx.x;
  if (i < NWORDS / 2) bm2[i] = make_ulonglong2(0ull, 0ull);
}

__global__ void mark_kernel(const float* __restrict__ pts, const int* __restrict__ bi,
                            unsigned long long* __restrict__ bm,
                            unsigned* __restrict__ upt, int n) {
  int i = blockIdx.x * blockDim.x + threadIdx.x;
  if (i >= n) return;
  // Bit-exact mirror of reference: floor((p - pmin)/vsize) in fp32 (sub/div/floor
  // cannot be contracted), int32 cast.
  float px = pts[3 * i + 0], py = pts[3 * i + 1], pz = pts[3 * i + 2];
  int vx = (int)floorf((px + 50.0f) / 0.1f);
  int vy = (int)floorf((py + 50.0f) / 0.1f);
  int vz = (int)floorf((pz + 5.0f) / 0.1f);
  bool valid = (vx >= 0) & (vy >= 0) & (vz >= 0) & (vx < GX) & (vy < GY) & (vz < GZ);
  unsigned u = 0xFFFFFFFFu;
  if (valid) {
    u = (unsigned)(bi[i] * GXYZ + vx * YZ + vy * GZ + vz);
    atomicOr(&bm[u >> 6], 1ull << (u & 63));
  }
  upt[i] = u;
}

__global__ void block_sum_kernel(const unsigned long long* __restrict__ bm,
                                 unsigned char* __restrict__ cnt,
                                 unsigned* __restrict__ bsums) {
  __shared__ unsigned s[256];
  int base = blockIdx.x * WPB;
  unsigned sum = 0;
  for (int w = base + threadIdx.x; w < base + WPB && w < NWORDS; w += 256) {
    unsigned p = (unsigned)__popcll(bm[w]);
    cnt[w] = (unsigned char)p;
    sum += p;
  }
  s[threadIdx.x] = sum;
  __syncthreads();
  for (int o = 128; o > 0; o >>= 1) {
    if (threadIdx.x < o) s[threadIdx.x] += s[threadIdx.x + o];
    __syncthreads();
  }
  if (threadIdx.x == 0) bsums[blockIdx.x] = s[0];
}

// Per-word exclusive prefix. Block offset computed per-block by reducing
// bsums[0..bid) (bsums is 10KB, L2-resident -> redundant reads are ~free).
// Block 0 additionally reduces all of bsums and writes n_voxels.
__global__ void word_prefix_kernel(const unsigned char* __restrict__ cnt,
                                   const unsigned* __restrict__ bsums,
                                   unsigned* __restrict__ prefix,
                                   float* __restrict__ out_nvox) {
  __shared__ unsigned s[256];
  __shared__ unsigned red[256];
  int tid = threadIdx.x;
  int bid = blockIdx.x;

  // 1) offset = sum of bsums[0..bid)
  unsigned part = 0;
  for (int k = tid; k < bid; k += 256) part += bsums[k];
  red[tid] = part;
  __syncthreads();
  for (int o = 128; o > 0; o >>= 1) {
    if (tid < o) red[tid] += red[tid + o];
    __syncthreads();
  }
  unsigned block_off = red[0];
  __syncthreads();

  // 2) block 0 also computes the grand total -> n_voxels
  if (bid == 0) {
    unsigned tpart = 0;
    for (int k = tid; k < NSCANB; k += 256) tpart += bsums[k];
    red[tid] = tpart;
    __syncthreads();
    for (int o = 128; o > 0; o >>= 1) {
      if (tid < o) red[tid] += red[tid + o];
      __syncthreads();
    }
    if (tid == 0) *out_nvox = (float)red[0];
  }

  // 3) intra-block per-word exclusive prefix from u8 counts
  int base = bid * WPB + tid * 8;  // 256 threads x 8 contiguous words
  unsigned c[8];
  unsigned t = 0;
  bool in = (base < NWORDS);  // base%8==0 and NWORDS%8==0 -> all-in or all-out
  if (in) {
    unsigned long long cc = *(const unsigned long long*)(cnt + base);
    #pragma unroll
    for (int j = 0; j < 8; j++) {
      unsigned p = (unsigned)((cc >> (8 * j)) & 0xFFull);
      c[j] = t;
      t += p;
    }
  } else {
    #pragma unroll
    for (int j = 0; j < 8; j++) c[j] = 0;
  }
  s[tid] = t;
  __syncthreads();
  for (int o = 1; o < 256; o <<= 1) {
    unsigned add = (tid >= o) ? s[tid - o] : 0u;
    __syncthreads();
    s[tid] += add;
    __syncthreads();
  }
  unsigned off = block_off + (s[tid] - t);
  if (in) {
    #pragma unroll
    for (int j = 0; j < 8; j++) prefix[base + j] = off + c[j];
  }
}

// Fused: blocks [0, en_blocks) enumerate set bits in ascending key order and
// write coords+centers at row=rank (rows < n_voxels); remaining blocks compute
// the per-point map and pad tail rows (rows >= n_voxels). Write sets disjoint.
__global__ void enum_map_kernel(const unsigned long long* __restrict__ bm,
                                const unsigned* __restrict__ prefix,
                                const unsigned* __restrict__ upt,
                                const float* __restrict__ nvox_f,
                                float* __restrict__ out_coords,
                                float* __restrict__ out_feats,
                                float* __restrict__ out_map,
                                int en_blocks, int n) {
  if ((int)blockIdx.x < en_blocks) {
    int w = blockIdx.x * 256 + threadIdx.x;
    if (w >= NWORDS) return;
    unsigned long long m = bm[w];
    if (!m) return;
    unsigned r = prefix[w];
    long long wbase = (long long)w << 6;
    while (m) {
      int b = __ffsll((long long)m) - 1;
      m &= m - 1;
      int u = (int)(wbase + b);
      int bat = u / GXYZ;
      int rem = u % GXYZ;
      int x = rem / YZ;
      int ry = rem % YZ;
      int y = ry / GZ;
      int z = ry % GZ;
      float* c = out_coords + (size_t)r * 4;
      c[0] = (float)bat; c[1] = (float)z; c[2] = (float)y; c[3] = (float)x;
      float* f = out_feats + (size_t)r * 3;
      f[0] = -50.0f + ((float)x + 0.5f) * 0.1f;
      f[1] = -50.0f + ((float)y + 0.5f) * 0.1f;
      f[2] = -5.0f + ((float)z + 0.5f) * 0.1f;
      r++;
    }
  } else {
    int i = ((int)blockIdx.x - en_blocks) * 256 + threadIdx.x;
    if (i >= n) return;
    unsigned u = upt[i];
    float r;
    if (u == 0xFFFFFFFFu) {
      r = -1.0f;
    } else {
      int w = (int)(u >> 6), b = (int)(u & 63u);
      unsigned long long below = bm[w] & ((1ull << b) - 1ull);
      r = (float)(prefix[w] + (unsigned)__popcll(below));
    }
    out_map[i] = r;
    int nv = (int)*nvox_f;
    if (i >= nv) {
      float* c = out_coords + (size_t)i * 4;
      c[0] = -1.0f; c[1] = -1.0f; c[2] = -1.0f; c[3] = -1.0f;
      float* f = out_feats + (size_t)i * 3;
      f[0] = 0.0f; f[1] = 0.0f; f[2] = 0.0f;
    }
  }
}

}  // namespace

extern "C" void kernel_launch(void* const* d_in, const int* in_sizes, int n_in,
                              void* d_out, int out_size, void* d_ws, size_t ws_size,
                              hipStream_t stream) {
  const int N = in_sizes[0] / 3;
  const float* pts = (const float*)d_in[0];
  const int* bi = (const int*)d_in[1];
  float* out = (float*)d_out;

  unsigned long long* bitmap = (unsigned long long*)d_ws;
  unsigned* prefix = (unsigned*)((char*)d_ws + OFF_PREFIX);
  unsigned char* cnt = (unsigned char*)((char*)d_ws + OFF_CNT);
  unsigned* bsums = (unsigned*)((char*)d_ws + OFF_BSUMS);
  unsigned* upt = (unsigned*)((char*)d_ws + OFF_UPT);

  float* out_coords = out;            // [N,4]
  float* out_feats  = out + 4LL * N;  // [N,3]
  float* out_map    = out + 7LL * N;  // [N]
  float* out_nvox   = out + 8LL * N;  // scalar

  const int en_blocks = (NWORDS + 255) / 256;
  const int map_blocks = (N + 255) / 256;

  zero_bitmap_kernel<<<(NWORDS / 2 + 255) / 256, 256, 0, stream>>>((ulonglong2*)bitmap);
  mark_kernel<<<map_blocks, 256, 0, stream>>>(pts, bi, bitmap, upt, N);
  block_sum_kernel<<<NSCANB, 256, 0, stream>>>(bitmap, cnt, bsums);
  word_prefix_kernel<<<NSCANB, 256, 0, stream>>>(cnt, bsums, prefix, out_nvox);
  enum_map_kernel<<<en_blocks + map_blocks, 256, 0, stream>>>(
      bitmap, prefix, upt, out_nvox, out_coords, out_feats, out_map, en_blocks, N);
}

// Round 6
// 194.544 us; speedup vs baseline: 1.3316x; 1.3316x over previous
//
#include <hip/hip_runtime.h>

// PointVoxelizer: bucketed sorted-unique over bounded key domain.
// combined = batch*GXYZ + x*YZ + y*GZ + z in [0, 3.2e8).
// Points are partitioned by key>>18 into 1221 buckets (2^18 cells = 32KB LDS
// bitmap each); all random access (bit-set, popcount, prefix, rank) happens
// in LDS. No global atomics (R5 profile: 2M scattered device atomicOr ran at
// ~25G/s = 80us; random bm/prefix gathers similar). Bucket order == key order
// == jnp.unique sort order.
//
// Dispatches:
//   k1_keys_hist  : keys -> upt; per-(chunk,bucket) LDS histogram -> hist[c][b]
//   k2a_chunk_pre : per-bucket exclusive prefix over chunks (wave shfl-scan) -> tot
//   k2b_scan_tot  : 1-block scan of tot -> boff[NB+1]
//   k3_scatter    : (key,idx) pairs into bucket regions; LDS cursors
//   k4_count      : per-bucket LDS bitmap -> dcnt[b]
//   k6_emit       : per-bucket rebuild + LDS word-prefix; enumerate -> rows;
//                   per-point rank -> map; pad blocks fill tail + n_voxels

namespace {

constexpr int GX = 1000, GY = 1000, GZ = 80;
constexpr int YZ = GY * GZ;                 // 80,000
constexpr int GXYZ = GX * YZ;               // 80,000,000
constexpr int TOTAL_CELLS = GXYZ * 4;       // 320,000,000 (< 2^31)
constexpr int BBITS = 18;
constexpr int BCELLS = 1 << BBITS;          // 262,144 cells / bucket
constexpr int NB = (TOTAL_CELLS + BCELLS - 1) >> BBITS;  // 1221
constexpr int BWORDS = BCELLS / 32;         // 8192 u32 (32KB LDS bitmap)
constexpr int NCHUNK = 1024;                // point chunks (must be %64==0)
static_assert(NCHUNK % 64 == 0, "k2a wave scan");

// ws layout (bytes):
//   [0,      8e6)   upt  u32[N]
//   [8e6,   24e6)   pk   u64[N]      (key<<32 | idx), 8B aligned
//   [24e6,  29e6)   hist u32[NCHUNK][NB]
//   [30e6,  ..)     tot  u32[NB]
//   [30.1e6,..)     boff u32[NB+1]
//   [30.2e6,..)     dcnt u32[NB]
constexpr size_t OFF_PK   = 8000000;
constexpr size_t OFF_HIST = 24000000;
constexpr size_t OFF_TOT  = 30000000;
constexpr size_t OFF_BOFF = 30100000;
constexpr size_t OFF_DCNT = 30200000;

__global__ void k1_keys_hist(const float* __restrict__ pts, const int* __restrict__ bi,
                             unsigned* __restrict__ upt, unsigned* __restrict__ hist,
                             float* __restrict__ out_map, int n, int cpb) {
  __shared__ unsigned h[NB];
  const int c = blockIdx.x;
  for (int b = threadIdx.x; b < NB; b += blockDim.x) h[b] = 0;
  __syncthreads();
  const int lo = c * cpb, hi = min(n, lo + cpb);
  for (int i = lo + threadIdx.x; i < hi; i += blockDim.x) {
    // Bit-exact mirror of reference: fp32 add/div/floor (non-contractible).
    float px = pts[3 * i + 0], py = pts[3 * i + 1], pz = pts[3 * i + 2];
    int vx = (int)floorf((px + 50.0f) / 0.1f);
    int vy = (int)floorf((py + 50.0f) / 0.1f);
    int vz = (int)floorf((pz + 5.0f) / 0.1f);
    bool valid = (vx >= 0) & (vy >= 0) & (vz >= 0) & (vx < GX) & (vy < GY) & (vz < GZ);
    unsigned u = 0xFFFFFFFFu;
    if (valid) {
      u = (unsigned)(bi[i] * GXYZ + vx * YZ + vy * GZ + vz);
      atomicAdd(&h[u >> BBITS], 1u);
    } else {
      out_map[i] = -1.0f;  // valid points written by k6
    }
    upt[i] = u;
  }
  __syncthreads();
  for (int b = threadIdx.x; b < NB; b += blockDim.x)
    hist[(size_t)c * NB + b] = h[b];  // row-contiguous flush, no atomics
}

// One wave per bucket: exclusive prefix of hist[*][b] across chunks (in place),
// bucket total -> tot[b]. Column loads are strided but LLC-resident.
__global__ void k2a_chunk_pre(unsigned* __restrict__ hist, unsigned* __restrict__ tot) {
  const int wid = (blockIdx.x * blockDim.x + threadIdx.x) >> 6;
  const int lane = threadIdx.x & 63;
  if (wid >= NB) return;
  unsigned run = 0;
  for (int c0 = 0; c0 < NCHUNK; c0 += 64) {
    const size_t idx = (size_t)(c0 + lane) * NB + wid;
    unsigned v = hist[idx];
    unsigned inc = v;
    for (int o = 1; o < 64; o <<= 1) {
      unsigned t = __shfl_up(inc, o);
      if (lane >= o) inc += t;
    }
    hist[idx] = run + inc - v;          // exclusive within bucket
    run += __shfl(inc, 63);
  }
  if (lane == 63) tot[wid] = run;
}

// Single-block exclusive scan of tot[NB] -> boff[NB+1].
__global__ void k2b_scan_tot(const unsigned* __restrict__ tot, unsigned* __restrict__ boff) {
  __shared__ unsigned s[1024];
  const int tid = threadIdx.x;
  unsigned v0 = (2 * tid     < NB) ? tot[2 * tid]     : 0u;
  unsigned v1 = (2 * tid + 1 < NB) ? tot[2 * tid + 1] : 0u;
  unsigned t = v0 + v1;
  s[tid] = t;
  __syncthreads();
  for (int o = 1; o < 1024; o <<= 1) {
    unsigned add = (tid >= o) ? s[tid - o] : 0u;
    __syncthreads();
    s[tid] += add;
    __syncthreads();
  }
  unsigned excl = s[tid] - t;
  if (2 * tid     < NB) boff[2 * tid]     = excl;
  if (2 * tid + 1 < NB) boff[2 * tid + 1] = excl + v0;
  if (tid == 1023) boff[NB] = s[1023];
}

// Scatter (key,idx) into bucket regions. Cursors live in LDS (order within a
// bucket region is irrelevant: buckets are treated as sets downstream).
__global__ void k3_scatter(const unsigned* __restrict__ upt, const unsigned* __restrict__ hist,
                           const unsigned* __restrict__ boff, unsigned long long* __restrict__ pk,
                           int n, int cpb) {
  __shared__ unsigned cur[NB];
  const int c = blockIdx.x;
  for (int b = threadIdx.x; b < NB; b += blockDim.x)
    cur[b] = boff[b] + hist[(size_t)c * NB + b];
  __syncthreads();
  const int lo = c * cpb, hi = min(n, lo + cpb);
  for (int i = lo + threadIdx.x; i < hi; i += blockDim.x) {
    unsigned u = upt[i];
    if (u == 0xFFFFFFFFu) continue;
    unsigned p = atomicAdd(&cur[u >> BBITS], 1u);
    pk[p] = ((unsigned long long)u << 32) | (unsigned)i;
  }
}

__global__ void __launch_bounds__(1024) k4_count(const unsigned long long* __restrict__ pk,
                                                 const unsigned* __restrict__ boff,
                                                 unsigned* __restrict__ dcnt) {
  __shared__ unsigned bits[BWORDS];
  __shared__ unsigned red[1024];
  const int b = blockIdx.x, tid = threadIdx.x;
  for (int w = tid; w < BWORDS; w += 1024) bits[w] = 0;
  __syncthreads();
  const unsigned lo = boff[b], hi = boff[b + 1];
  const unsigned base = (unsigned)b << BBITS;
  for (unsigned p = lo + tid; p < hi; p += 1024) {
    unsigned local = (unsigned)(pk[p] >> 32) - base;
    atomicOr(&bits[local >> 5], 1u << (local & 31));
  }
  __syncthreads();
  unsigned cnt = 0;
  for (int w = tid; w < BWORDS; w += 1024) cnt += __popc(bits[w]);
  red[tid] = cnt;
  __syncthreads();
  for (int o = 512; o > 0; o >>= 1) {
    if (tid < o) red[tid] += red[tid + o];
    __syncthreads();
  }
  if (tid == 0) dcnt[b] = red[0];
}

__global__ void __launch_bounds__(1024) k6_emit(
    const unsigned long long* __restrict__ pk, const unsigned* __restrict__ boff,
    const unsigned* __restrict__ dcnt, float* __restrict__ out_coords,
    float* __restrict__ out_feats, float* __restrict__ out_map,
    float* __restrict__ out_nvox, int n) {
  __shared__ unsigned bits[BWORDS];  // 32KB
  __shared__ unsigned wpre[BWORDS];  // 32KB
  __shared__ unsigned s[1024];       //  4KB  (68KB -> 2 blocks/CU)
  const int tid = threadIdx.x;
  const int bid = blockIdx.x;

  if (bid >= NB) {
    // pad role: n_voxels = sum(dcnt); rows [nv, n) get coords=-1, feats=0
    unsigned part = 0;
    for (int k = tid; k < NB; k += 1024) part += dcnt[k];
    s[tid] = part;
    __syncthreads();
    for (int o = 512; o > 0; o >>= 1) {
      if (tid < o) s[tid] += s[tid + o];
      __syncthreads();
    }
    const unsigned nv = s[0];
    if (bid == NB && tid == 0) *out_nvox = (float)nv;
    const int row = (bid - NB) * 1024 + tid;
    if (row < n && (unsigned)row >= nv) {
      float* c = out_coords + (size_t)row * 4;
      c[0] = -1.0f; c[1] = -1.0f; c[2] = -1.0f; c[3] = -1.0f;
      float* f = out_feats + (size_t)row * 3;
      f[0] = 0.0f; f[1] = 0.0f; f[2] = 0.0f;
    }
    return;
  }

  // drank = voxel-rank base of this bucket = sum(dcnt[0..bid))  (L2-resident)
  unsigned part = 0;
  for (int k = tid; k < bid; k += 1024) part += dcnt[k];
  s[tid] = part;
  __syncthreads();
  for (int o = 512; o > 0; o >>= 1) {
    if (tid < o) s[tid] += s[tid + o];
    __syncthreads();
  }
  const unsigned drank = s[0];
  __syncthreads();

  // rebuild bucket bitmap in LDS
  for (int w = tid; w < BWORDS; w += 1024) bits[w] = 0;
  __syncthreads();
  const unsigned lo = boff[bid], hi = boff[bid + 1];
  const unsigned base = (unsigned)bid << BBITS;
  for (unsigned p = lo + tid; p < hi; p += 1024) {
    unsigned local = (unsigned)(pk[p] >> 32) - base;
    atomicOr(&bits[local >> 5], 1u << (local & 31));
  }
  __syncthreads();

  // per-word exclusive popcount prefix (thread owns 8 contiguous words)
  const int wb = tid * 8;
  unsigned c8[8];
  unsigned t = 0;
  #pragma unroll
  for (int j = 0; j < 8; j++) {
    unsigned p = __popc(bits[wb + j]);
    c8[j] = t;
    t += p;
  }
  s[tid] = t;
  __syncthreads();
  for (int o = 1; o < 1024; o <<= 1) {
    unsigned add = (tid >= o) ? s[tid - o] : 0u;
    __syncthreads();
    s[tid] += add;
    __syncthreads();
  }
  const unsigned excl = s[tid] - t;
  #pragma unroll
  for (int j = 0; j < 8; j++) wpre[wb + j] = excl + c8[j];
  __syncthreads();

  // enumerate set bits in order -> rows [drank, drank+dcnt[bid])
  #pragma unroll
  for (int j = 0; j < 8; j++) {
    const int w = wb + j;
    unsigned m = bits[w];
    unsigned r = drank + wpre[w];
    const unsigned lbase = (unsigned)w << 5;
    while (m) {
      int bit = __ffs(m) - 1;
      m &= m - 1;
      unsigned u = base + lbase + (unsigned)bit;
      int bat = (int)(u / (unsigned)GXYZ);
      int rem = (int)(u % (unsigned)GXYZ);
      int x = rem / YZ, ry = rem % YZ;
      int y = ry / GZ, z = ry % GZ;
      float* cc = out_coords + (size_t)r * 4;
      cc[0] = (float)bat; cc[1] = (float)z; cc[2] = (float)y; cc[3] = (float)x;
      float* ff = out_feats + (size_t)r * 3;
      ff[0] = -50.0f + ((float)x + 0.5f) * 0.1f;
      ff[1] = -50.0f + ((float)y + 0.5f) * 0.1f;
      ff[2] = -5.0f + ((float)z + 0.5f) * 0.1f;
      r++;
    }
  }

  // per-point rank -> map (all lookups in LDS)
  for (unsigned p = lo + tid; p < hi; p += 1024) {
    unsigned long long e = pk[p];
    unsigned local = (unsigned)(e >> 32) - base;
    unsigned w = local >> 5;
    unsigned r = drank + wpre[w] + (unsigned)__popc(bits[w] & ((1u << (local & 31)) - 1u));
    out_map[(unsigned)e] = (float)r;
  }
}

}  // namespace

extern "C" void kernel_launch(void* const* d_in, const int* in_sizes, int n_in,
                              void* d_out, int out_size, void* d_ws, size_t ws_size,
                              hipStream_t stream) {
  const int N = in_sizes[0] / 3;
  const float* pts = (const float*)d_in[0];
  const int* bi = (const int*)d_in[1];
  float* out = (float*)d_out;

  unsigned* upt = (unsigned*)d_ws;
  unsigned long long* pk = (unsigned long long*)((char*)d_ws + OFF_PK);
  unsigned* hist = (unsigned*)((char*)d_ws + OFF_HIST);
  unsigned* tot  = (unsigned*)((char*)d_ws + OFF_TOT);
  unsigned* boff = (unsigned*)((char*)d_ws + OFF_BOFF);
  unsigned* dcnt = (unsigned*)((char*)d_ws + OFF_DCNT);

  float* out_coords = out;            // [N,4]
  float* out_feats  = out + 4LL * N;  // [N,3]
  float* out_map    = out + 7LL * N;  // [N]
  float* out_nvox   = out + 8LL * N;  // scalar

  const int cpb = (N + NCHUNK - 1) / NCHUNK;
  const int pad_blocks = (N + 1023) / 1024;

  k1_keys_hist<<<NCHUNK, 256, 0, stream>>>(pts, bi, upt, hist, out_map, N, cpb);
  k2a_chunk_pre<<<(NB * 64 + 255) / 256, 256, 0, stream>>>(hist, tot);
  k2b_scan_tot<<<1, 1024, 0, stream>>>(tot, boff);
  k3_scatter<<<NCHUNK, 256, 0, stream>>>(upt, hist, boff, pk, N, cpb);
  k4_count<<<NB, 1024, 0, stream>>>(pk, boff, dcnt);
  k6_emit<<<NB + pad_blocks, 1024, 0, stream>>>(pk, boff, dcnt, out_coords,
                                                out_feats, out_map, out_nvox, N);
}